// Round 1
// baseline (719.571 us; speedup 1.0000x reference)
//
#include <hip/hip_runtime.h>
#include <math.h>

// B=2,H=16,S=1024,D=64 attention with additive biases + mask -> -1e9.
// Outputs context (B,H,S,D) and attn (B,H,S,S), f32.
//
// R3 design: 512-thread / 8-wave blocks, 32 q-rows per block. Same per-wave
// QK^T (registers, 256-k LDS chunks, swizzled) and 64-lane-shuffle softmax as
// R2 -> attn math identical. PV no longer stages P in LDS: each wave re-reads
// its P rows from the just-written attn output (L2-hit, workgroup-coherent
// after __syncthreads), two 16-row halves, k-split 128/wave, cross-wave
// reduce through the dead K-tile LDS. LDS/wave halves -> 16 waves/CU (50%).
#define S_LEN 1024
#define D_DIM 64
#define NEGV  (-1.0e9f)

__global__ __launch_bounds__(512, 4)
void attn_bias_fused(const float* __restrict__ Q, const float* __restrict__ K,
                     const float* __restrict__ V, const int* __restrict__ mif,
                     const float* __restrict__ iat, const float* __restrict__ iaf,
                     float* __restrict__ ctx, float* __restrict__ attn)
{
    // 64 KB: K chunk (transposed+swizzled) during QK; reused as
    // scratch[16][16][64] f32 for the cross-wave PV reduction.
    __shared__ float4 Kt4[D_DIM][64];
    // 8 KB: Qst[64][32] (transposed Q tile).
    __shared__ float  SB[2048];

    float (*Qst)[32] = (float(*)[32])SB;
    float* scr = (float*)Kt4;

    const int tid  = threadIdx.x;
    const int wave = tid >> 6;            // 0..7
    const int lane = tid & 63;
    const int bh   = blockIdx.x >> 5;     // 0..31
    const int qb   = (blockIdx.x & 31) << 5;   // 32-row q tile

    const float* Qb = Q + ((size_t)(bh * S_LEN + qb)) * D_DIM;
    const float* Kb = K + ((size_t)bh * S_LEN) * D_DIM;
    const float* Vb = V + ((size_t)bh * S_LEN) * D_DIM;

    // ---- stage Q tile transposed: Qst[d][q], q in [0,32) ----
    {
        int q = tid >> 4, l = tid & 15;   // q 0..31, l 0..15
        float4 v = *(const float4*)(Qb + (size_t)q * D_DIM + l * 4);
        Qst[4 * l + 0][q] = v.x;
        Qst[4 * l + 1][q] = v.y;
        Qst[4 * l + 2][q] = v.z;
        Qst[4 * l + 3][q] = v.w;
    }

    const int kg = lane;   // k quad within 256-chunk
    const int qg = wave;   // 4 q rows per wave

    float4 sc[16];         // sc[c*4+i]: row qg*4+i, k = c*256 + kg*4 .. +3

    // =================== QK^T + bias + mask -> registers ===================
    #pragma unroll
    for (int c = 0; c < 4; ++c) {
        __syncthreads();   // Kt4 reuse fence (also covers Qst staging at c=0)
        {
            int l = tid & 15, kr0 = tid >> 4;   // kr0 0..31
            #pragma unroll
            for (int i = 0; i < 8; ++i) {
                int kk = i * 32 + kr0;
                float4 v = *(const float4*)(Kb + (size_t)(c * 256 + kk) * D_DIM + l * 4);
                int cc  = (kk >> 2) ^ (l & 7);
                int sub = kk & 3;
                ((float*)&Kt4[4 * l + 0][cc])[sub] = v.x;
                ((float*)&Kt4[4 * l + 1][cc])[sub] = v.y;
                ((float*)&Kt4[4 * l + 2][cc])[sub] = v.z;
                ((float*)&Kt4[4 * l + 3][cc])[sub] = v.w;
            }
        }
        __syncthreads();

        // prefetch bias/mask (independent; hides under the FMA loop)
        float4 bt[4], bf[4];
        int4   bm[4];
        #pragma unroll
        for (int i = 0; i < 4; ++i) {
            size_t off = ((size_t)(bh * S_LEN + qb + qg * 4 + i)) * S_LEN + c * 256 + kg * 4;
            bt[i] = *(const float4*)(iat + off);
            bf[i] = *(const float4*)(iaf + off);
            bm[i] = *(const int4*)(mif + off);
        }

        float4 a0 = {0.f, 0.f, 0.f, 0.f}, a1 = a0, a2 = a0, a3 = a0;
        #pragma unroll 16
        for (int d = 0; d < D_DIM; ++d) {
            float4 kv = Kt4[d][kg ^ ((d >> 2) & 7)];          // conflict-free b128
            float4 qv = *(const float4*)&Qst[d][qg * 4];       // wave-uniform broadcast
            a0.x = fmaf(qv.x, kv.x, a0.x); a0.y = fmaf(qv.x, kv.y, a0.y);
            a0.z = fmaf(qv.x, kv.z, a0.z); a0.w = fmaf(qv.x, kv.w, a0.w);
            a1.x = fmaf(qv.y, kv.x, a1.x); a1.y = fmaf(qv.y, kv.y, a1.y);
            a1.z = fmaf(qv.y, kv.z, a1.z); a1.w = fmaf(qv.y, kv.w, a1.w);
            a2.x = fmaf(qv.z, kv.x, a2.x); a2.y = fmaf(qv.z, kv.y, a2.y);
            a2.z = fmaf(qv.z, kv.z, a2.z); a2.w = fmaf(qv.z, kv.w, a2.w);
            a3.x = fmaf(qv.w, kv.x, a3.x); a3.y = fmaf(qv.w, kv.y, a3.y);
            a3.z = fmaf(qv.w, kv.z, a3.z); a3.w = fmaf(qv.w, kv.w, a3.w);
        }

        float4 av[4] = {a0, a1, a2, a3};
        #pragma unroll
        for (int i = 0; i < 4; ++i) {
            float4 s = av[i];
            float4 t = bt[i], f = bf[i];
            int4   m = bm[i];
            s.x = m.x ? NEGV : fmaf(s.x, 0.125f, t.x + f.x);
            s.y = m.y ? NEGV : fmaf(s.y, 0.125f, t.y + f.y);
            s.z = m.z ? NEGV : fmaf(s.z, 0.125f, t.z + f.z);
            s.w = m.w ? NEGV : fmaf(s.w, 0.125f, t.w + f.w);
            sc[c * 4 + i] = s;
        }
    }

    // =================== softmax in registers (64-lane shuffles) ===================
    {
        float mx[4], sum[4], rinv[4];
        #pragma unroll
        for (int i = 0; i < 4; ++i) {
            float m = -INFINITY;
            #pragma unroll
            for (int c = 0; c < 4; ++c) {
                float4 v = sc[c * 4 + i];
                m = fmaxf(m, fmaxf(fmaxf(v.x, v.y), fmaxf(v.z, v.w)));
            }
            #pragma unroll
            for (int s = 1; s < 64; s <<= 1) m = fmaxf(m, __shfl_xor(m, s, 64));
            mx[i] = m;
        }
        #pragma unroll
        for (int i = 0; i < 4; ++i) {
            float sm = 0.f;
            #pragma unroll
            for (int c = 0; c < 4; ++c) {
                float4 v = sc[c * 4 + i];
                v.x = __expf(v.x - mx[i]);   // all-masked row -> exp(0)=1 -> uniform, matches ref
                v.y = __expf(v.y - mx[i]);
                v.z = __expf(v.z - mx[i]);
                v.w = __expf(v.w - mx[i]);
                sc[c * 4 + i] = v;
                sm += v.x + v.y + v.z + v.w;
            }
            #pragma unroll
            for (int s = 1; s < 64; s <<= 1) sm += __shfl_xor(sm, s, 64);
            sum[i] = sm;
            rinv[i] = 1.f / sm;
        }
        // normalize; write attn (coalesced 1 KiB/row). P is re-read from here in PV.
        #pragma unroll
        for (int i = 0; i < 4; ++i) {
            int r = qg * 4 + i;
            float* arow = attn + ((size_t)(bh * S_LEN + qb + r)) * S_LEN;
            #pragma unroll
            for (int c = 0; c < 4; ++c) {
                float4 v = sc[c * 4 + i];
                v.x *= rinv[i]; v.y *= rinv[i]; v.z *= rinv[i]; v.w *= rinv[i];
                *(float4*)(arow + c * 256 + kg * 4) = v;
            }
        }
        (void)sum;
    }
    __syncthreads();   // attn writes visible block-wide; Kt4 reads done -> scr free

    // =================== context = P @ V (P from attn, L2-hit) ===================
    // Two halves of 16 q rows. Wave w covers k in [w*128,(w+1)*128) for all 16
    // rows of the half; lanes: dg = d-quad, ks = k-sub; ks-groups reduced by
    // shuffle, k-ranges reduced cross-wave through scr.
    {
        const int dg = lane & 15;
        const int ks = lane >> 4;
        for (int h = 0; h < 2; ++h) {
            float4 acc[16];
            #pragma unroll
            for (int q = 0; q < 16; ++q) acc[q] = make_float4(0.f, 0.f, 0.f, 0.f);

            const float* pb = attn + ((size_t)(bh * S_LEN + qb + h * 16)) * S_LEN;

            #pragma unroll 2
            for (int i = 0; i < 8; ++i) {
                int k0 = wave * 128 + i * 16 + ks * 4;
                const float* vrow = Vb + (size_t)k0 * D_DIM + dg * 4;
                float4 v0 = *(const float4*)(vrow + 0 * D_DIM);
                float4 v1 = *(const float4*)(vrow + 1 * D_DIM);
                float4 v2 = *(const float4*)(vrow + 2 * D_DIM);
                float4 v3 = *(const float4*)(vrow + 3 * D_DIM);
                #pragma unroll
                for (int q = 0; q < 16; ++q) {
                    float4 p = *(const float4*)(pb + (size_t)q * S_LEN + k0);
                    float4 a = acc[q];
                    a.x = fmaf(p.x, v0.x, a.x); a.x = fmaf(p.y, v1.x, a.x);
                    a.x = fmaf(p.z, v2.x, a.x); a.x = fmaf(p.w, v3.x, a.x);
                    a.y = fmaf(p.x, v0.y, a.y); a.y = fmaf(p.y, v1.y, a.y);
                    a.y = fmaf(p.z, v2.y, a.y); a.y = fmaf(p.w, v3.y, a.y);
                    a.z = fmaf(p.x, v0.z, a.z); a.z = fmaf(p.y, v1.z, a.z);
                    a.z = fmaf(p.z, v2.z, a.z); a.z = fmaf(p.w, v3.z, a.z);
                    a.w = fmaf(p.x, v0.w, a.w); a.w = fmaf(p.y, v1.w, a.w);
                    a.w = fmaf(p.z, v2.w, a.w); a.w = fmaf(p.w, v3.w, a.w);
                    acc[q] = a;
                }
            }

            // reduce the 4 ks-groups within the wave; lanes 0..15 end complete
            #pragma unroll
            for (int q = 0; q < 16; ++q) {
                acc[q].x += __shfl_xor(acc[q].x, 16, 64);
                acc[q].y += __shfl_xor(acc[q].y, 16, 64);
                acc[q].z += __shfl_xor(acc[q].z, 16, 64);
                acc[q].w += __shfl_xor(acc[q].w, 16, 64);
                acc[q].x += __shfl_xor(acc[q].x, 32, 64);
                acc[q].y += __shfl_xor(acc[q].y, 32, 64);
                acc[q].z += __shfl_xor(acc[q].z, 32, 64);
                acc[q].w += __shfl_xor(acc[q].w, 32, 64);
            }

            // park per-wave partials; halves use disjoint scr regions (no barrier)
            if (lane < 16) {
                #pragma unroll
                for (int q = 0; q < 16; ++q)
                    *(float4*)&scr[((h * 8 + wave) * 16 + q) * 64 + dg * 4] = acc[q];
            }
        }
    }
    __syncthreads();

    // cross-wave reduction: 512 threads cover 32 rows x 16 d-quads
    {
        int qq = tid >> 4;          // 0..31 (row within tile)
        int dq = tid & 15;
        int h  = qq >> 4, q = qq & 15;
        float4 r = make_float4(0.f, 0.f, 0.f, 0.f);
        #pragma unroll
        for (int w = 0; w < 8; ++w) {
            float4 v = *(const float4*)&scr[((h * 8 + w) * 16 + q) * 64 + dq * 4];
            r.x += v.x; r.y += v.y; r.z += v.z; r.w += v.w;
        }
        *(float4*)(ctx + ((size_t)(bh * S_LEN + qb + qq)) * D_DIM + dq * 4) = r;
    }
}

extern "C" void kernel_launch(void* const* d_in, const int* in_sizes, int n_in,
                              void* d_out, int out_size, void* d_ws, size_t ws_size,
                              hipStream_t stream) {
    const float* Q   = (const float*)d_in[0];
    const float* K   = (const float*)d_in[1];
    const float* V   = (const float*)d_in[2];
    const int*   mif = (const int*)d_in[4];    // attn_mask_if
    const float* iat = (const float*)d_in[5];
    const float* iaf = (const float*)d_in[6];

    float* ctx  = (float*)d_out;
    float* attn = (float*)d_out + (size_t)2 * 16 * 1024 * 64;

    dim3 grid(1024), block(512);
    hipLaunchKernelGGL(attn_bias_fused, grid, block, 0, stream,
                       Q, K, V, mif, iat, iaf, ctx, attn);
}

// Round 2
// 584.819 us; speedup vs baseline: 1.2304x; 1.2304x over previous
//
#include <hip/hip_runtime.h>
#include <math.h>

// B=2,H=16,S=1024,D=64 attention with additive biases + mask -> -1e9.
// Outputs context (B,H,S,D) and attn (B,H,S,S), f32.
//
// R4 = R3 structure with the register budget fixed.
// R3's __launch_bounds__(512,4) forced VGPR=64 -> sc[16] (64 VGPRs) spilled to
// scratch (+193 MB writes, +210 MB reads, 2x slowdown). (512,2) allows >=128
// VGPRs (proven sufficient by R2's identical per-wave code) while LDS (72 KB)
// still caps at 2 blocks/CU = 16 waves/CU (2x R2's occupancy).
#define S_LEN 1024
#define D_DIM 64
#define NEGV  (-1.0e9f)

__global__ __launch_bounds__(512, 2)
void attn_bias_fused(const float* __restrict__ Q, const float* __restrict__ K,
                     const float* __restrict__ V, const int* __restrict__ mif,
                     const float* __restrict__ iat, const float* __restrict__ iaf,
                     float* __restrict__ ctx, float* __restrict__ attn)
{
    // 64 KB: K chunk (transposed+swizzled) during QK; reused as
    // scratch[16][16][64] f32 for the cross-wave PV reduction.
    __shared__ float4 Kt4[D_DIM][64];
    // 8 KB: Qst[64][32] (transposed Q tile).
    __shared__ float  SB[2048];

    float (*Qst)[32] = (float(*)[32])SB;
    float* scr = (float*)Kt4;

    const int tid  = threadIdx.x;
    const int wave = tid >> 6;            // 0..7
    const int lane = tid & 63;
    const int bh   = blockIdx.x >> 5;     // 0..31
    const int qb   = (blockIdx.x & 31) << 5;   // 32-row q tile

    const float* Qb = Q + ((size_t)(bh * S_LEN + qb)) * D_DIM;
    const float* Kb = K + ((size_t)bh * S_LEN) * D_DIM;
    const float* Vb = V + ((size_t)bh * S_LEN) * D_DIM;

    // ---- stage Q tile transposed: Qst[d][q], q in [0,32) ----
    {
        int q = tid >> 4, l = tid & 15;   // q 0..31, l 0..15
        float4 v = *(const float4*)(Qb + (size_t)q * D_DIM + l * 4);
        Qst[4 * l + 0][q] = v.x;
        Qst[4 * l + 1][q] = v.y;
        Qst[4 * l + 2][q] = v.z;
        Qst[4 * l + 3][q] = v.w;
    }

    const int kg = lane;   // k quad within 256-chunk
    const int qg = wave;   // 4 q rows per wave

    float4 sc[16];         // sc[c*4+i]: row qg*4+i, k = c*256 + kg*4 .. +3

    // =================== QK^T + bias + mask -> registers ===================
    #pragma unroll
    for (int c = 0; c < 4; ++c) {
        __syncthreads();   // Kt4 reuse fence (also covers Qst staging at c=0)
        {
            int l = tid & 15, kr0 = tid >> 4;   // kr0 0..31
            #pragma unroll
            for (int i = 0; i < 8; ++i) {
                int kk = i * 32 + kr0;
                float4 v = *(const float4*)(Kb + (size_t)(c * 256 + kk) * D_DIM + l * 4);
                int cc  = (kk >> 2) ^ (l & 7);
                int sub = kk & 3;
                ((float*)&Kt4[4 * l + 0][cc])[sub] = v.x;
                ((float*)&Kt4[4 * l + 1][cc])[sub] = v.y;
                ((float*)&Kt4[4 * l + 2][cc])[sub] = v.z;
                ((float*)&Kt4[4 * l + 3][cc])[sub] = v.w;
            }
        }
        __syncthreads();

        // prefetch bias/mask (independent; hides under the FMA loop)
        float4 bt[4], bf[4];
        int4   bm[4];
        #pragma unroll
        for (int i = 0; i < 4; ++i) {
            size_t off = ((size_t)(bh * S_LEN + qb + qg * 4 + i)) * S_LEN + c * 256 + kg * 4;
            bt[i] = *(const float4*)(iat + off);
            bf[i] = *(const float4*)(iaf + off);
            bm[i] = *(const int4*)(mif + off);
        }

        float4 a0 = {0.f, 0.f, 0.f, 0.f}, a1 = a0, a2 = a0, a3 = a0;
        #pragma unroll 16
        for (int d = 0; d < D_DIM; ++d) {
            float4 kv = Kt4[d][kg ^ ((d >> 2) & 7)];          // conflict-free b128
            float4 qv = *(const float4*)&Qst[d][qg * 4];       // wave-uniform broadcast
            a0.x = fmaf(qv.x, kv.x, a0.x); a0.y = fmaf(qv.x, kv.y, a0.y);
            a0.z = fmaf(qv.x, kv.z, a0.z); a0.w = fmaf(qv.x, kv.w, a0.w);
            a1.x = fmaf(qv.y, kv.x, a1.x); a1.y = fmaf(qv.y, kv.y, a1.y);
            a1.z = fmaf(qv.y, kv.z, a1.z); a1.w = fmaf(qv.y, kv.w, a1.w);
            a2.x = fmaf(qv.z, kv.x, a2.x); a2.y = fmaf(qv.z, kv.y, a2.y);
            a2.z = fmaf(qv.z, kv.z, a2.z); a2.w = fmaf(qv.z, kv.w, a2.w);
            a3.x = fmaf(qv.w, kv.x, a3.x); a3.y = fmaf(qv.w, kv.y, a3.y);
            a3.z = fmaf(qv.w, kv.z, a3.z); a3.w = fmaf(qv.w, kv.w, a3.w);
        }

        float4 av[4] = {a0, a1, a2, a3};
        #pragma unroll
        for (int i = 0; i < 4; ++i) {
            float4 s = av[i];
            float4 t = bt[i], f = bf[i];
            int4   m = bm[i];
            s.x = m.x ? NEGV : fmaf(s.x, 0.125f, t.x + f.x);
            s.y = m.y ? NEGV : fmaf(s.y, 0.125f, t.y + f.y);
            s.z = m.z ? NEGV : fmaf(s.z, 0.125f, t.z + f.z);
            s.w = m.w ? NEGV : fmaf(s.w, 0.125f, t.w + f.w);
            sc[c * 4 + i] = s;
        }
    }

    // =================== softmax in registers (64-lane shuffles) ===================
    {
        float mx[4], sum[4], rinv[4];
        #pragma unroll
        for (int i = 0; i < 4; ++i) {
            float m = -INFINITY;
            #pragma unroll
            for (int c = 0; c < 4; ++c) {
                float4 v = sc[c * 4 + i];
                m = fmaxf(m, fmaxf(fmaxf(v.x, v.y), fmaxf(v.z, v.w)));
            }
            #pragma unroll
            for (int s = 1; s < 64; s <<= 1) m = fmaxf(m, __shfl_xor(m, s, 64));
            mx[i] = m;
        }
        #pragma unroll
        for (int i = 0; i < 4; ++i) {
            float sm = 0.f;
            #pragma unroll
            for (int c = 0; c < 4; ++c) {
                float4 v = sc[c * 4 + i];
                v.x = __expf(v.x - mx[i]);   // all-masked row -> exp(0)=1 -> uniform, matches ref
                v.y = __expf(v.y - mx[i]);
                v.z = __expf(v.z - mx[i]);
                v.w = __expf(v.w - mx[i]);
                sc[c * 4 + i] = v;
                sm += v.x + v.y + v.z + v.w;
            }
            #pragma unroll
            for (int s = 1; s < 64; s <<= 1) sm += __shfl_xor(sm, s, 64);
            sum[i] = sm;
            rinv[i] = 1.f / sm;
        }
        // normalize; write attn (coalesced 1 KiB/row). P is re-read from here in PV.
        #pragma unroll
        for (int i = 0; i < 4; ++i) {
            int r = qg * 4 + i;
            float* arow = attn + ((size_t)(bh * S_LEN + qb + r)) * S_LEN;
            #pragma unroll
            for (int c = 0; c < 4; ++c) {
                float4 v = sc[c * 4 + i];
                v.x *= rinv[i]; v.y *= rinv[i]; v.z *= rinv[i]; v.w *= rinv[i];
                *(float4*)(arow + c * 256 + kg * 4) = v;
            }
        }
        (void)sum;
    }
    __syncthreads();   // attn writes visible block-wide; Kt4 reads done -> scr free

    // =================== context = P @ V (P from attn, L2-hit) ===================
    // Two halves of 16 q rows. Wave w covers k in [w*128,(w+1)*128) for all 16
    // rows of the half; lanes: dg = d-quad, ks = k-sub; ks-groups reduced by
    // shuffle, k-ranges reduced cross-wave through scr.
    {
        const int dg = lane & 15;
        const int ks = lane >> 4;
        for (int h = 0; h < 2; ++h) {
            float4 acc[16];
            #pragma unroll
            for (int q = 0; q < 16; ++q) acc[q] = make_float4(0.f, 0.f, 0.f, 0.f);

            const float* pb = attn + ((size_t)(bh * S_LEN + qb + h * 16)) * S_LEN;

            #pragma unroll 2
            for (int i = 0; i < 8; ++i) {
                int k0 = wave * 128 + i * 16 + ks * 4;
                const float* vrow = Vb + (size_t)k0 * D_DIM + dg * 4;
                float4 v0 = *(const float4*)(vrow + 0 * D_DIM);
                float4 v1 = *(const float4*)(vrow + 1 * D_DIM);
                float4 v2 = *(const float4*)(vrow + 2 * D_DIM);
                float4 v3 = *(const float4*)(vrow + 3 * D_DIM);
                #pragma unroll
                for (int q = 0; q < 16; ++q) {
                    float4 p = *(const float4*)(pb + (size_t)q * S_LEN + k0);
                    float4 a = acc[q];
                    a.x = fmaf(p.x, v0.x, a.x); a.x = fmaf(p.y, v1.x, a.x);
                    a.x = fmaf(p.z, v2.x, a.x); a.x = fmaf(p.w, v3.x, a.x);
                    a.y = fmaf(p.x, v0.y, a.y); a.y = fmaf(p.y, v1.y, a.y);
                    a.y = fmaf(p.z, v2.y, a.y); a.y = fmaf(p.w, v3.y, a.y);
                    a.z = fmaf(p.x, v0.z, a.z); a.z = fmaf(p.y, v1.z, a.z);
                    a.z = fmaf(p.z, v2.z, a.z); a.z = fmaf(p.w, v3.z, a.z);
                    a.w = fmaf(p.x, v0.w, a.w); a.w = fmaf(p.y, v1.w, a.w);
                    a.w = fmaf(p.z, v2.w, a.w); a.w = fmaf(p.w, v3.w, a.w);
                    acc[q] = a;
                }
            }

            // reduce the 4 ks-groups within the wave; lanes 0..15 end complete
            #pragma unroll
            for (int q = 0; q < 16; ++q) {
                acc[q].x += __shfl_xor(acc[q].x, 16, 64);
                acc[q].y += __shfl_xor(acc[q].y, 16, 64);
                acc[q].z += __shfl_xor(acc[q].z, 16, 64);
                acc[q].w += __shfl_xor(acc[q].w, 16, 64);
                acc[q].x += __shfl_xor(acc[q].x, 32, 64);
                acc[q].y += __shfl_xor(acc[q].y, 32, 64);
                acc[q].z += __shfl_xor(acc[q].z, 32, 64);
                acc[q].w += __shfl_xor(acc[q].w, 32, 64);
            }

            // park per-wave partials; halves use disjoint scr regions (no barrier)
            if (lane < 16) {
                #pragma unroll
                for (int q = 0; q < 16; ++q)
                    *(float4*)&scr[((h * 8 + wave) * 16 + q) * 64 + dg * 4] = acc[q];
            }
        }
    }
    __syncthreads();

    // cross-wave reduction: 512 threads cover 32 rows x 16 d-quads
    {
        int qq = tid >> 4;          // 0..31 (row within tile)
        int dq = tid & 15;
        int h  = qq >> 4, q = qq & 15;
        float4 r = make_float4(0.f, 0.f, 0.f, 0.f);
        #pragma unroll
        for (int w = 0; w < 8; ++w) {
            float4 v = *(const float4*)&scr[((h * 8 + w) * 16 + q) * 64 + dq * 4];
            r.x += v.x; r.y += v.y; r.z += v.z; r.w += v.w;
        }
        *(float4*)(ctx + ((size_t)(bh * S_LEN + qb + qq)) * D_DIM + dq * 4) = r;
    }
}

extern "C" void kernel_launch(void* const* d_in, const int* in_sizes, int n_in,
                              void* d_out, int out_size, void* d_ws, size_t ws_size,
                              hipStream_t stream) {
    const float* Q   = (const float*)d_in[0];
    const float* K   = (const float*)d_in[1];
    const float* V   = (const float*)d_in[2];
    const int*   mif = (const int*)d_in[4];    // attn_mask_if
    const float* iat = (const float*)d_in[5];
    const float* iaf = (const float*)d_in[6];

    float* ctx  = (float*)d_out;
    float* attn = (float*)d_out + (size_t)2 * 16 * 1024 * 64;

    dim3 grid(1024), block(512);
    hipLaunchKernelGGL(attn_bias_fused, grid, block, 0, stream,
                       Q, K, V, mif, iat, iaf, ctx, attn);
}